// Round 3
// baseline (993.193 us; speedup 1.0000x reference)
//
#include <hip/hip_runtime.h>
#include <hip/hip_bf16.h>
#include <math.h>

// Problem dims
#define B_SZ 16
#define L_SZ 8192
#define DM   256
#define SS   256
#define FF   1024
#define M_SZ (B_SZ * L_SZ)      // 131072 rows
#define TCH  128                // scan chunk length
#define NCH  (L_SZ / TCH)       // 64 chunks per batch

// GEMM tile
#define BM 128
#define BN 128
#define BK 32

typedef __bf16 bf16x8 __attribute__((ext_vector_type(8)));
typedef float  f32x4  __attribute__((ext_vector_type(4)));

// ---------------------------------------------------------------- async 16B global->LDS
__device__ __forceinline__ void gld_lds16(const __bf16* g, __bf16* l) {
  __builtin_amdgcn_global_load_lds(
      (const __attribute__((address_space(1))) unsigned int*)g,
      (__attribute__((address_space(3))) unsigned int*)l, 16, 0, 0);
}

// ---------------------------------------------------------------- branchless exact-GELU
// erf via Abramowitz-Stegun 7.1.26 (max abs err 1.5e-7, well below bf16 output ulp).
__device__ __forceinline__ float gelu_exact_fast(float t) {
  const float at = fabsf(t);
  const float a  = at * 0.70710678118654752f;
  const float k  = __builtin_amdgcn_rcpf(fmaf(0.3275911f, a, 1.0f));
  float P = fmaf(1.061405429f, k, -1.453152027f);
  P = fmaf(P, k, 1.421413741f);
  P = fmaf(P, k, -0.284496736f);
  P = fmaf(P, k, 0.254829592f);
  P = P * k;
  const float e = __expf(-a * a);          // v_exp_f32 path
  const float half_t  = 0.5f * t;
  const float half_at = 0.5f * at;
  return fmaf(-half_at, P * e, half_t + half_at);
}

// ---------------------------------------------------------------- weight prep
__global__ void prep_kernel(const float* __restrict__ nu_log, const float* __restrict__ th_log,
                            const float* __restrict__ ga_log,
                            const float* __restrict__ B_re, const float* __restrict__ B_im,
                            const float* __restrict__ C_re, const float* __restrict__ C_im,
                            const float* __restrict__ Dmat,
                            const float* __restrict__ W_fc, const float* __restrict__ W_proj,
                            __bf16* __restrict__ Wb, __bf16* __restrict__ Wz,
                            __bf16* __restrict__ Wfc, __bf16* __restrict__ Wp,
                            float* __restrict__ lam)
{
  const int idx = blockIdx.x * 256 + threadIdx.x;   // 0 .. 262143
  if (idx < SS) {
    float la = expf(-expf(nu_log[idx]));
    float th = expf(th_log[idx]);
    lam[2*idx]   = la * cosf(th);
    lam[2*idx+1] = la * sinf(th);
  }
  if (idx < SS*DM) {
    int s = idx >> 8, d = idx & 255;
    float eg = expf(ga_log[s]);
    Wb[(size_t)(2*s)*DM + d]   = (__bf16)(B_re[idx] * eg);
    Wb[(size_t)(2*s+1)*DM + d] = (__bf16)(B_im[idx] * eg);
  }
  if (idx < DM*SS) {
    int o = idx >> 8, s = idx & 255;
    Wz[(size_t)o*768 + 2*s]     = (__bf16)( C_re[idx]);
    Wz[(size_t)o*768 + 2*s + 1] = (__bf16)(-C_im[idx]);
    Wz[(size_t)o*768 + 512 + s] = (__bf16)( Dmat[idx]);   // s acts as d here
  }
  if (idx < FF*DM) {
    int f = idx >> 8, d = idx & 255;                 // Wfc[f][d] = W_fc[d][f]
    Wfc[idx] = (__bf16)(W_fc[(size_t)d*FF + f]);
    int o = idx >> 10, f2 = idx & 1023;              // Wp[o][f2] = W_proj[f2][o]
    Wp[idx] = (__bf16)(W_proj[(size_t)f2*DM + o]);
  }
}

// ---------------------------------------------------------------- x (fp32) -> bf16 into S_all cols [512,768)
__global__ __launch_bounds__(256) void convert_x(const float* __restrict__ x, __bf16* __restrict__ S_all)
{
  const long i = ((long)blockIdx.x * 256 + threadIdx.x) * 4;  // over 33554432
  float4 v = *(const float4*)(x + i);
  const long m = i >> 8;
  const int  d = (int)(i & 255);
  union { __bf16 h[4]; uint2 u; } pk;
  pk.h[0] = (__bf16)v.x; pk.h[1] = (__bf16)v.y; pk.h[2] = (__bf16)v.z; pk.h[3] = (__bf16)v.w;
  *(uint2*)(S_all + m*768 + 512 + d) = pk.u;
}

// ---------------------------------------------------------------- bf16 MFMA GEMM, B^T (N,K) weights
// LDS-port-relief version:
//  - A tile: global_load_lds double-buffered (HBM stream, latency covered).
//  - B (small L2-hot weights): fragments loaded DIRECT global->register with a
//    one-iteration prefetch (bgN). Removes 24 KB/block-iter of LDS traffic
//    (the port was ~80% busy = the measured bottleneck).
//  - Epilogue staged through LDS (free after loop): coalesced 16B stores and
//    coalesced resid/bias loads instead of 64 scattered 2-4B accesses.
// MODE 1: store bf16 | MODE 2: bias + exact gelu -> bf16 | MODE 3: bias + resid -> f32
template<int K, int LDA, int LDC, int MODE, int NT>
__global__ __launch_bounds__(256, 2) void gemm_bt(const __bf16* __restrict__ A,
                                                  const __bf16* __restrict__ Bw,
                                                  void* __restrict__ Cout,
                                                  const float* __restrict__ bias,
                                                  const float* __restrict__ resid)
{
  // [0,8192): A-tile double buffer (2 x 128x32 bf16). Whole 32 KB reused as f32
  // staging (64 rows x 128 cols) in the epilogue.
  __shared__ __attribute__((aligned(16))) __bf16 smem[16384];

  const int tid  = threadIdx.x;
  const int lane = tid & 63;
  const int wave = tid >> 6;
  const int wm = (wave & 1) * 64;
  const int wn = (wave >> 1) * 64;

  constexpr int PER = 16 * NT;              // blocks per super-band (power of 2)
  const int blk = blockIdx.x;
  const int sb  = blk / PER;
  const int rem = blk & (PER - 1);
  const long m0 = (long)((sb << 4) + (rem & 15)) * BM;
  const long n0 = (long)(rem >> 4) * BN;

  f32x4 acc[4][4] = {};

  const int r  = tid >> 2;         // 0..63 (row within 64-row half)
  const int c8 = (tid & 3) * 8;    // k element offset of this thread's 16B chunk
  const __bf16* gA = A + (m0 + r) * (long)LDA + c8;

  const int ar = lane & 15;
  const int ak = (lane >> 4) * 8;

  // B fragment base pointers (per j): row n0+wn+j*16+ar, k-offset ak
  const __bf16* gB0 = Bw + (n0 + wn +  0 + ar) * (long)K + ak;
  const __bf16* gB1 = Bw + (n0 + wn + 16 + ar) * (long)K + ak;
  const __bf16* gB2 = Bw + (n0 + wn + 32 + ar) * (long)K + ak;
  const __bf16* gB3 = Bw + (n0 + wn + 48 + ar) * (long)K + ak;

  constexpr int NK = K / BK;

  // prologue: stage A tile 0; load B frags for step 0
  gld_lds16(gA,                  &smem[tid * 8]);
  gld_lds16(gA + 64 * (long)LDA, &smem[2048 + tid * 8]);
  gA += BK;
  bf16x8 bg[4], bgN[4];
  bg[0] = *(const bf16x8*)gB0;
  bg[1] = *(const bf16x8*)gB1;
  bg[2] = *(const bf16x8*)gB2;
  bg[3] = *(const bf16x8*)gB3;
  __syncthreads();

  int cur = 0;
  #pragma unroll 2
  for (int i = 0; i < NK; ++i) {
    const __bf16* sAc = smem + cur * 4096;
    if (i + 1 < NK) {
      __bf16* sAn = smem + (cur ^ 1) * 4096;
      gld_lds16(gA,                  &sAn[tid * 8]);
      gld_lds16(gA + 64 * (long)LDA, &sAn[2048 + tid * 8]);
      gA += BK;
      const long ko = (long)(i + 1) * BK;
      bgN[0] = *(const bf16x8*)(gB0 + ko);
      bgN[1] = *(const bf16x8*)(gB1 + ko);
      bgN[2] = *(const bf16x8*)(gB2 + ko);
      bgN[3] = *(const bf16x8*)(gB3 + ko);
    }

    bf16x8 af[4];
    #pragma unroll
    for (int ii = 0; ii < 4; ++ii)
      af[ii] = *(const bf16x8*)&sAc[(wm + ii * 16 + ar) * BK + ak];
    #pragma unroll
    for (int ii = 0; ii < 4; ++ii)
      #pragma unroll
      for (int j = 0; j < 4; ++j)
        acc[ii][j] = __builtin_amdgcn_mfma_f32_16x16x32_bf16(af[ii], bg[j], acc[ii][j], 0, 0, 0);

    #pragma unroll
    for (int j = 0; j < 4; ++j) bg[j] = bgN[j];
    __syncthreads();               // drains next A-tile loads; frees sAc
    cur ^= 1;
  }

  // ------------------------------------------------ staged epilogue
  // acc layout: D row = (lane>>4)*4 + rr, col = lane&15  [measured m89/m91]
  // Stage 64-row halves as f32 in LDS with (row&7)<<2 column-XOR (both sides
  // 2-way = free), then read back row-contiguous and store coalesced.
  float* ldsF = (float*)smem;
  const int col_l = lane & 15;
  const int row_l = (lane >> 4) * 4;
  const int er  = tid >> 2;            // 0..63: row within half
  const int ec0 = (tid & 3) * 32;      // 32-col quarter
  const int esw = (er & 7) << 2;

  #pragma unroll
  for (int h = 0; h < 2; ++h) {
    if (wm == h * 64) {
      #pragma unroll
      for (int i = 0; i < 4; ++i)
        #pragma unroll
        for (int j = 0; j < 4; ++j) {
          const int colb = wn + j * 16 + col_l;
          #pragma unroll
          for (int rr = 0; rr < 4; ++rr) {
            const int rowb = i * 16 + row_l + rr;
            ldsF[rowb * 128 + (colb ^ ((rowb & 7) << 2))] = acc[i][j][rr];
          }
        }
    }
    __syncthreads();
    {
      const long grow = m0 + h * 64 + er;
      f32x4 vv[8];
      #pragma unroll
      for (int q = 0; q < 8; ++q)
        vv[q] = *(const f32x4*)&ldsF[er * 128 + ((ec0 + q * 4) ^ esw)];

      if constexpr (MODE == 1) {
        #pragma unroll
        for (int q = 0; q < 4; ++q) {
          union { __bf16 hh[8]; uint4 u; } pk;
          #pragma unroll
          for (int e = 0; e < 4; ++e) {
            pk.hh[e]     = (__bf16)vv[2*q][e];
            pk.hh[4 + e] = (__bf16)vv[2*q+1][e];
          }
          *(uint4*)((__bf16*)Cout + grow * (long)LDC + n0 + ec0 + q * 8) = pk.u;
        }
      } else if constexpr (MODE == 2) {
        #pragma unroll
        for (int q = 0; q < 4; ++q) {
          const f32x4 b0 = *(const f32x4*)(bias + n0 + ec0 + q * 8);
          const f32x4 b1 = *(const f32x4*)(bias + n0 + ec0 + q * 8 + 4);
          union { __bf16 hh[8]; uint4 u; } pk;
          #pragma unroll
          for (int e = 0; e < 4; ++e) {
            pk.hh[e]     = (__bf16)gelu_exact_fast(vv[2*q][e]   + b0[e]);
            pk.hh[4 + e] = (__bf16)gelu_exact_fast(vv[2*q+1][e] + b1[e]);
          }
          *(uint4*)((__bf16*)Cout + grow * (long)LDC + n0 + ec0 + q * 8) = pk.u;
        }
      } else {
        #pragma unroll
        for (int q = 0; q < 8; ++q) {
          const long cidx = grow * (long)LDC + n0 + ec0 + q * 4;
          const f32x4 rv = *(const f32x4*)(resid + cidx);
          const f32x4 bv = *(const f32x4*)(bias + n0 + ec0 + q * 4);
          f32x4 o;
          #pragma unroll
          for (int e = 0; e < 4; ++e) o[e] = vv[q][e] + bv[e] + rv[e];
          *(f32x4*)((float*)Cout + cidx) = o;
        }
      }
    }
    __syncthreads();
  }
}

// ---------------------------------------------------------------- scan kernels
// Bu layout: (M, 512) bf16, col 2s=re, 2s+1=im. Thread s loads 4B (2 bf16) per row.
#define CSTEP(vr, vi) { float nr_ = fmaf(lr, sr, fmaf(-li, si, (vr))); \
                        float ni_ = fmaf(lr, si, fmaf( li, sr, (vi))); sr = nr_; si = ni_; }

union bupk { unsigned int u; __bf16 h[2]; };

// Pass A: per-chunk carry with s_init = 0.
__global__ __launch_bounds__(256) void scan_carry(const __bf16* __restrict__ Bu,
                                                  const float* __restrict__ lam,
                                                  float2* __restrict__ carr)
{
  const int s  = threadIdx.x;
  const int bc = blockIdx.x;                       // b*NCH + c
  const float lr = lam[2*s], li = lam[2*s+1];
  const unsigned int* bu = (const unsigned int*)(Bu + (size_t)bc * (TCH * 512)) + s; // row stride 256 uints
  float sr = 0.f, si = 0.f;
  bupk v0, v1, v2, v3;
  v0.u = bu[0]; v1.u = bu[256]; v2.u = bu[512]; v3.u = bu[768];
  for (int t = 0; t < TCH - 4; t += 4) {
    bupk n0, n1, n2, n3;
    n0.u = bu[(t+4)*256]; n1.u = bu[(t+5)*256]; n2.u = bu[(t+6)*256]; n3.u = bu[(t+7)*256];
    CSTEP((float)v0.h[0], (float)v0.h[1]); CSTEP((float)v1.h[0], (float)v1.h[1]);
    CSTEP((float)v2.h[0], (float)v2.h[1]); CSTEP((float)v3.h[0], (float)v3.h[1]);
    v0 = n0; v1 = n1; v2 = n2; v3 = n3;
  }
  CSTEP((float)v0.h[0], (float)v0.h[1]); CSTEP((float)v1.h[0], (float)v1.h[1]);
  CSTEP((float)v2.h[0], (float)v2.h[1]); CSTEP((float)v3.h[0], (float)v3.h[1]);
  carr[(size_t)bc * 256 + s] = make_float2(sr, si);
}

// Pass B: exclusive prefix over chunks, operator p' = lam^TCH * p + carry
__global__ __launch_bounds__(256) void scan_prefix(const float2* __restrict__ carr,
                                                   const float* __restrict__ lam,
                                                   float2* __restrict__ pre)
{
  const int s = threadIdx.x;
  const int b = blockIdx.x;
  float ar = lam[2*s], ai = lam[2*s+1];            // lam^TCH by squaring: TCH=128=2^7
  #pragma unroll
  for (int i = 0; i < 7; ++i) { float nr = ar*ar - ai*ai, ni = 2.f*ar*ai; ar = nr; ai = ni; }
  float pr = 0.f, pi = 0.f;
  for (int c = 0; c < NCH; ++c) {
    const size_t off = (size_t)(b * NCH + c) * 256 + s;
    pre[off] = make_float2(pr, pi);
    float2 cv = carr[off];
    float nr = fmaf(ar, pr, fmaf(-ai, pi, cv.x));
    float ni = fmaf(ar, pi, fmaf( ai, pr, cv.y));
    pr = nr; pi = ni;
  }
}

// Pass C: re-scan with init = prefix, write inclusive states as bf16 into S_all cols [0,512)
__global__ __launch_bounds__(256) void scan_apply(const __bf16* __restrict__ Bu,
                                                  const float* __restrict__ lam,
                                                  const float2* __restrict__ pre,
                                                  __bf16* __restrict__ S_all)
{
  const int s  = threadIdx.x;
  const int bc = blockIdx.x;
  const float lr = lam[2*s], li = lam[2*s+1];
  float2 p = pre[(size_t)bc * 256 + s];
  float sr = p.x, si = p.y;
  const unsigned int* bu = (const unsigned int*)(Bu + (size_t)bc * (TCH * 512)) + s;
  __bf16* outp = S_all + (size_t)bc * (TCH * 768) + 2 * s;
  #define APSTEP(v, t) { CSTEP((float)(v).h[0], (float)(v).h[1]); \
    union { __bf16 h[2]; unsigned int u; } pk_; pk_.h[0] = (__bf16)sr; pk_.h[1] = (__bf16)si; \
    *(unsigned int*)(outp + (size_t)(t) * 768) = pk_.u; }
  bupk v0, v1, v2, v3;
  v0.u = bu[0]; v1.u = bu[256]; v2.u = bu[512]; v3.u = bu[768];
  for (int t = 0; t < TCH - 4; t += 4) {
    bupk n0, n1, n2, n3;
    n0.u = bu[(t+4)*256]; n1.u = bu[(t+5)*256]; n2.u = bu[(t+6)*256]; n3.u = bu[(t+7)*256];
    APSTEP(v0, t); APSTEP(v1, t+1); APSTEP(v2, t+2); APSTEP(v3, t+3);
    v0 = n0; v1 = n1; v2 = n2; v3 = n3;
  }
  { const int t = TCH - 4; APSTEP(v0, t); APSTEP(v1, t+1); APSTEP(v2, t+2); APSTEP(v3, t+3); }
  #undef APSTEP
}

// ---------------------------------------------------------------- launch
extern "C" void kernel_launch(void* const* d_in, const int* in_sizes, int n_in,
                              void* d_out, int out_size, void* d_ws, size_t ws_size,
                              hipStream_t stream)
{
  const float* x      = (const float*)d_in[0];
  const float* nu_log = (const float*)d_in[1];
  const float* th_log = (const float*)d_in[2];
  const float* ga_log = (const float*)d_in[3];
  const float* B_re   = (const float*)d_in[4];
  const float* B_im   = (const float*)d_in[5];
  const float* C_re   = (const float*)d_in[6];
  const float* C_im   = (const float*)d_in[7];
  const float* Dmat   = (const float*)d_in[8];
  const float* W_fc   = (const float*)d_in[9];
  const float* b_fc   = (const float*)d_in[10];
  const float* W_proj = (const float*)d_in[11];
  const float* b_proj = (const float*)d_in[12];

  // ws layout (bytes):
  //   S_all : (M, 768) bf16 @ 0            201326592  [states interleaved | x_bf16]
  //   Bu    : (M, 512) bf16 @ 201326592    134217728  (dead after scan_apply)
  //   Hbuf  : (M,1024) bf16 @ 201326592    268435456  (overlaps Bu; written by gemm3 after Bu dead)
  //   Wb/Wz/Wfc/Wp/lam      @ 469762048    ~1.7 MB
  char* ws = (char*)d_ws;
  __bf16* S_all = (__bf16*)(ws);
  __bf16* Bu    = (__bf16*)(ws + 201326592);
  __bf16* Hbuf  = (__bf16*)(ws + 201326592);
  __bf16* Wb    = (__bf16*)(ws + 469762048);
  __bf16* Wz    = (__bf16*)(ws + 470024192);
  __bf16* Wfc   = (__bf16*)(ws + 470417408);
  __bf16* Wp    = (__bf16*)(ws + 470941696);
  float*  lam   = (float*) (ws + 471465984);
  if (ws_size < 471468032ULL) return;  // insufficient scratch: fail visibly

  // d_out (134 MB) doubles as scratch before the final GEMM overwrites all of it:
  char* ob = (char*)d_out;
  __bf16* Zbuf = (__bf16*)ob;                    // (M,256) bf16 = 67108864 B
  float2* carr = (float2*)(ob + 67108864);       // 16*64*256*8 = 2 MB
  float2* pre  = (float2*)(ob + 69206016);       // 2 MB  (end 71303168 < 134217728)

  prep_kernel<<<1024, 256, 0, stream>>>(nu_log, th_log, ga_log, B_re, B_im,
                                        C_re, C_im, Dmat, W_fc, W_proj,
                                        Wb, Wz, Wfc, Wp, lam);
  convert_x<<<M_SZ * DM / (256 * 4), 256, 0, stream>>>(x, S_all);

  // Bu = x @ [gamma*B_re ; gamma*B_im]^T   (M,512) bf16
  gemm_bt<256, 768, 512, 1, 4><<<(M_SZ / BM) * 4, 256, 0, stream>>>(S_all + 512, Wb, Bu, nullptr, nullptr);

  scan_carry <<<B_SZ * NCH, 256, 0, stream>>>(Bu, lam, carr);
  scan_prefix<<<B_SZ,       256, 0, stream>>>(carr, lam, pre);
  scan_apply <<<B_SZ * NCH, 256, 0, stream>>>(Bu, lam, pre, S_all);

  // z = Re(C s) + x D^T   -> bf16
  gemm_bt<768, 768, 256, 1, 2><<<(M_SZ / BM) * 2, 256, 0, stream>>>(S_all, Wz, Zbuf, nullptr, nullptr);
  // h = gelu(z W_fc + b_fc) -> bf16 (reuses Bu region)
  gemm_bt<256, 256, 1024, 2, 8><<<(M_SZ / BM) * 8, 256, 0, stream>>>(Zbuf, Wfc, Hbuf, b_fc, nullptr);
  // out = h W_proj + b_proj + x -> f32
  gemm_bt<1024, 1024, 256, 3, 2><<<(M_SZ / BM) * 2, 256, 0, stream>>>(Hbuf, Wp, d_out, b_proj, x);
}

// Round 4
// 783.809 us; speedup vs baseline: 1.2671x; 1.2671x over previous
//
#include <hip/hip_runtime.h>
#include <hip/hip_bf16.h>
#include <math.h>

// Problem dims
#define B_SZ 16
#define L_SZ 8192
#define DM   256
#define SS   256
#define FF   1024
#define M_SZ (B_SZ * L_SZ)      // 131072 rows
#define TCH  128                // scan chunk length
#define NCH  (L_SZ / TCH)       // 64 chunks per batch

// GEMM tile
#define BM 128
#define BN 128
#define BK 32

typedef __bf16 bf16x8 __attribute__((ext_vector_type(8)));
typedef float  f32x4  __attribute__((ext_vector_type(4)));

// ---------------------------------------------------------------- async 16B global->LDS
__device__ __forceinline__ void gld_lds16(const __bf16* g, __bf16* l) {
  __builtin_amdgcn_global_load_lds(
      (const __attribute__((address_space(1))) unsigned int*)g,
      (__attribute__((address_space(3))) unsigned int*)l, 16, 0, 0);
}

// ---------------------------------------------------------------- branchless exact-GELU
// erf via Abramowitz-Stegun 7.1.26 (max abs err 1.5e-7, well below bf16 output ulp).
__device__ __forceinline__ float gelu_exact_fast(float t) {
  const float at = fabsf(t);
  const float a  = at * 0.70710678118654752f;
  const float k  = __builtin_amdgcn_rcpf(fmaf(0.3275911f, a, 1.0f));
  float P = fmaf(1.061405429f, k, -1.453152027f);
  P = fmaf(P, k, 1.421413741f);
  P = fmaf(P, k, -0.284496736f);
  P = fmaf(P, k, 0.254829592f);
  P = P * k;
  const float e = __expf(-a * a);          // v_exp_f32 path
  const float half_t  = 0.5f * t;
  const float half_at = 0.5f * at;
  return fmaf(-half_at, P * e, half_t + half_at);
}

// ---------------------------------------------------------------- weight prep
__global__ void prep_kernel(const float* __restrict__ nu_log, const float* __restrict__ th_log,
                            const float* __restrict__ ga_log,
                            const float* __restrict__ B_re, const float* __restrict__ B_im,
                            const float* __restrict__ C_re, const float* __restrict__ C_im,
                            const float* __restrict__ Dmat,
                            const float* __restrict__ W_fc, const float* __restrict__ W_proj,
                            __bf16* __restrict__ Wb, __bf16* __restrict__ Wz,
                            __bf16* __restrict__ Wfc, __bf16* __restrict__ Wp,
                            float* __restrict__ lam)
{
  const int idx = blockIdx.x * 256 + threadIdx.x;   // 0 .. 262143
  if (idx < SS) {
    float la = expf(-expf(nu_log[idx]));
    float th = expf(th_log[idx]);
    lam[2*idx]   = la * cosf(th);
    lam[2*idx+1] = la * sinf(th);
  }
  if (idx < SS*DM) {
    int s = idx >> 8, d = idx & 255;
    float eg = expf(ga_log[s]);
    Wb[(size_t)(2*s)*DM + d]   = (__bf16)(B_re[idx] * eg);
    Wb[(size_t)(2*s+1)*DM + d] = (__bf16)(B_im[idx] * eg);
  }
  if (idx < DM*SS) {
    int o = idx >> 8, s = idx & 255;
    Wz[(size_t)o*768 + 2*s]     = (__bf16)( C_re[idx]);
    Wz[(size_t)o*768 + 2*s + 1] = (__bf16)(-C_im[idx]);
    Wz[(size_t)o*768 + 512 + s] = (__bf16)( Dmat[idx]);   // s acts as d here
  }
  if (idx < FF*DM) {
    int f = idx >> 8, d = idx & 255;                 // Wfc[f][d] = W_fc[d][f]
    Wfc[idx] = (__bf16)(W_fc[(size_t)d*FF + f]);
    int o = idx >> 10, f2 = idx & 1023;              // Wp[o][f2] = W_proj[f2][o]
    Wp[idx] = (__bf16)(W_proj[(size_t)f2*DM + o]);
  }
}

// ---------------------------------------------------------------- x (fp32) -> bf16 into S_all cols [512,768)
__global__ __launch_bounds__(256) void convert_x(const float* __restrict__ x, __bf16* __restrict__ S_all)
{
  const long i = ((long)blockIdx.x * 256 + threadIdx.x) * 4;  // over 33554432
  float4 v = *(const float4*)(x + i);
  const long m = i >> 8;
  const int  d = (int)(i & 255);
  union { __bf16 h[4]; uint2 u; } pk;
  pk.h[0] = (__bf16)v.x; pk.h[1] = (__bf16)v.y; pk.h[2] = (__bf16)v.z; pk.h[3] = (__bf16)v.w;
  *(uint2*)(S_all + m*768 + 512 + d) = pk.u;
}

// ---------------------------------------------------------------- bf16 MFMA GEMM, B^T (N,K) weights
// 4-deep async pipeline (catalog T4: counted vmcnt, never 0 in steady loop):
//   prologue: STAGE tiles 0,1,2 into bufs 0,1,2           (12 loads in flight)
//   iter i  : s_waitcnt vmcnt(8)   -> oldest tile (i) landed for this wave
//             s_barrier            -> landed for ALL waves; also: everyone is
//                                     done READING buf[(i-1)&3] (program order),
//                                     so staging tile i+3 into buf[(i+3)&3]
//                                     (same buffer) after the barrier is safe
//             STAGE tile i+3       -> back to 12 in flight
//             ds_read buf[i&3] + MFMA (compiler inserts lgkmcnt waits)
// 3 tiles of prefetch distance ~= 3 full compute phases ~= 1000+ cy, covering
// the ~900 cy HBM latency that made R1/R2's 1-deep dbuf NULL (vmcnt(0) drain).
// MODE 1: store bf16 | MODE 2: bias + exact gelu -> bf16 | MODE 3: bias + resid -> f32
template<int K, int LDA, int LDC, int MODE, int NT>
__global__ __launch_bounds__(256, 2) void gemm_bt(const __bf16* __restrict__ A,
                                                  const __bf16* __restrict__ Bw,
                                                  void* __restrict__ Cout,
                                                  const float* __restrict__ bias,
                                                  const float* __restrict__ resid)
{
  // 4 buffers x (A 128x32 + B 128x32) bf16 = 64 KB.
  // sA buf q at smem + q*4096, sB buf q at smem + 16384 + q*4096.
  __shared__ __attribute__((aligned(16))) __bf16 smem[32768];

  const int tid  = threadIdx.x;
  const int lane = tid & 63;
  const int wave = tid >> 6;
  const int wm = (wave & 1) * 64;
  const int wn = (wave >> 1) * 64;

  constexpr int PER = 16 * NT;              // blocks per super-band (power of 2)
  const int blk = blockIdx.x;
  const int sb  = blk / PER;
  const int rem = blk & (PER - 1);
  const long m0 = (long)((sb << 4) + (rem & 15)) * BM;
  const long n0 = (long)(rem >> 4) * BN;

  f32x4 acc[4][4] = {};

  const int r  = tid >> 2;         // 0..63 (row within 64-row half)
  const int c8 = (tid & 3) * 8;    // k element offset of this thread's 16B chunk
  const __bf16* gA = A  + (m0 + r) * (long)LDA + c8;
  const __bf16* gB = Bw + (n0 + r) * (long)K   + c8;

  const int ar = lane & 15;
  const int ak = (lane >> 4) * 8;

  constexpr int NK = K / BK;       // 8 / 8 / 24 / 32 for the four GEMMs

  #define STAGE(t, q) { \
    const long ko_ = (long)(t) * BK; \
    __bf16* sa_ = smem + (q) * 4096; \
    __bf16* sb_ = smem + 16384 + (q) * 4096; \
    gld_lds16(gA + ko_,                  &sa_[tid * 8]); \
    gld_lds16(gA + ko_ + 64 * (long)LDA, &sa_[2048 + tid * 8]); \
    gld_lds16(gB + ko_,                  &sb_[tid * 8]); \
    gld_lds16(gB + ko_ + 64 * (long)K,   &sb_[2048 + tid * 8]); }

  // prologue: 3 tiles in flight
  STAGE(0, 0);
  STAGE(1, 1);
  STAGE(2, 2);

  #pragma unroll 4
  for (int i = 0; i < NK; ++i) {
    if (i < NK - 2)       { asm volatile("s_waitcnt vmcnt(8)" ::: "memory"); }
    else if (i == NK - 2) { asm volatile("s_waitcnt vmcnt(4)" ::: "memory"); }
    else                  { asm volatile("s_waitcnt vmcnt(0)" ::: "memory"); }
    __builtin_amdgcn_s_barrier();

    if (i + 3 < NK) STAGE(i + 3, (i + 3) & 3);

    const __bf16* sAc = smem + (i & 3) * 4096;
    const __bf16* sBc = smem + 16384 + (i & 3) * 4096;

    bf16x8 af[4], bg[4];
    #pragma unroll
    for (int ii = 0; ii < 4; ++ii)
      af[ii] = *(const bf16x8*)&sAc[(wm + ii * 16 + ar) * BK + ak];
    #pragma unroll
    for (int j = 0; j < 4; ++j)
      bg[j] = *(const bf16x8*)&sBc[(wn + j * 16 + ar) * BK + ak];
    #pragma unroll
    for (int ii = 0; ii < 4; ++ii)
      #pragma unroll
      for (int j = 0; j < 4; ++j)
        acc[ii][j] = __builtin_amdgcn_mfma_f32_16x16x32_bf16(af[ii], bg[j], acc[ii][j], 0, 0, 0);
  }
  #undef STAGE

  // Epilogue: D row = (lane>>4)*4 + reg, col = lane&15   [measured m89/m91]
  const int col_l = lane & 15;
  const int row_l = (lane >> 4) * 4;
  #pragma unroll
  for (int i = 0; i < 4; ++i) {
    #pragma unroll
    for (int j = 0; j < 4; ++j) {
      const long row = m0 + wm + i * 16 + row_l;
      const long col = n0 + wn + j * 16 + col_l;
      #pragma unroll
      for (int rr = 0; rr < 4; ++rr) {
        const float v = acc[i][j][rr];
        const long idx = (row + rr) * (long)LDC + col;
        if constexpr (MODE == 1) {
          ((__bf16*)Cout)[idx] = (__bf16)v;
        } else if constexpr (MODE == 2) {
          const float t = v + bias[col];
          ((__bf16*)Cout)[idx] = (__bf16)gelu_exact_fast(t);
        } else {
          ((float*)Cout)[idx] = v + bias[col] + resid[idx];
        }
      }
    }
  }
}

// ---------------------------------------------------------------- scan kernels
// Bu layout: (M, 512) bf16, col 2s=re, 2s+1=im. Thread s loads 4B (2 bf16) per row.
#define CSTEP(vr, vi) { float nr_ = fmaf(lr, sr, fmaf(-li, si, (vr))); \
                        float ni_ = fmaf(lr, si, fmaf( li, sr, (vi))); sr = nr_; si = ni_; }

union bupk { unsigned int u; __bf16 h[2]; };

// Pass A: per-chunk carry with s_init = 0.
__global__ __launch_bounds__(256) void scan_carry(const __bf16* __restrict__ Bu,
                                                  const float* __restrict__ lam,
                                                  float2* __restrict__ carr)
{
  const int s  = threadIdx.x;
  const int bc = blockIdx.x;                       // b*NCH + c
  const float lr = lam[2*s], li = lam[2*s+1];
  const unsigned int* bu = (const unsigned int*)(Bu + (size_t)bc * (TCH * 512)) + s; // row stride 256 uints
  float sr = 0.f, si = 0.f;
  bupk v0, v1, v2, v3;
  v0.u = bu[0]; v1.u = bu[256]; v2.u = bu[512]; v3.u = bu[768];
  for (int t = 0; t < TCH - 4; t += 4) {
    bupk n0, n1, n2, n3;
    n0.u = bu[(t+4)*256]; n1.u = bu[(t+5)*256]; n2.u = bu[(t+6)*256]; n3.u = bu[(t+7)*256];
    CSTEP((float)v0.h[0], (float)v0.h[1]); CSTEP((float)v1.h[0], (float)v1.h[1]);
    CSTEP((float)v2.h[0], (float)v2.h[1]); CSTEP((float)v3.h[0], (float)v3.h[1]);
    v0 = n0; v1 = n1; v2 = n2; v3 = n3;
  }
  CSTEP((float)v0.h[0], (float)v0.h[1]); CSTEP((float)v1.h[0], (float)v1.h[1]);
  CSTEP((float)v2.h[0], (float)v2.h[1]); CSTEP((float)v3.h[0], (float)v3.h[1]);
  carr[(size_t)bc * 256 + s] = make_float2(sr, si);
}

// Pass B: exclusive prefix over chunks, operator p' = lam^TCH * p + carry
__global__ __launch_bounds__(256) void scan_prefix(const float2* __restrict__ carr,
                                                   const float* __restrict__ lam,
                                                   float2* __restrict__ pre)
{
  const int s = threadIdx.x;
  const int b = blockIdx.x;
  float ar = lam[2*s], ai = lam[2*s+1];            // lam^TCH by squaring: TCH=128=2^7
  #pragma unroll
  for (int i = 0; i < 7; ++i) { float nr = ar*ar - ai*ai, ni = 2.f*ar*ai; ar = nr; ai = ni; }
  float pr = 0.f, pi = 0.f;
  for (int c = 0; c < NCH; ++c) {
    const size_t off = (size_t)(b * NCH + c) * 256 + s;
    pre[off] = make_float2(pr, pi);
    float2 cv = carr[off];
    float nr = fmaf(ar, pr, fmaf(-ai, pi, cv.x));
    float ni = fmaf(ar, pi, fmaf( ai, pr, cv.y));
    pr = nr; pi = ni;
  }
}

// Pass C: re-scan with init = prefix, write inclusive states as bf16 into S_all cols [0,512)
__global__ __launch_bounds__(256) void scan_apply(const __bf16* __restrict__ Bu,
                                                  const float* __restrict__ lam,
                                                  const float2* __restrict__ pre,
                                                  __bf16* __restrict__ S_all)
{
  const int s  = threadIdx.x;
  const int bc = blockIdx.x;
  const float lr = lam[2*s], li = lam[2*s+1];
  float2 p = pre[(size_t)bc * 256 + s];
  float sr = p.x, si = p.y;
  const unsigned int* bu = (const unsigned int*)(Bu + (size_t)bc * (TCH * 512)) + s;
  __bf16* outp = S_all + (size_t)bc * (TCH * 768) + 2 * s;
  #define APSTEP(v, t) { CSTEP((float)(v).h[0], (float)(v).h[1]); \
    union { __bf16 h[2]; unsigned int u; } pk_; pk_.h[0] = (__bf16)sr; pk_.h[1] = (__bf16)si; \
    *(unsigned int*)(outp + (size_t)(t) * 768) = pk_.u; }
  bupk v0, v1, v2, v3;
  v0.u = bu[0]; v1.u = bu[256]; v2.u = bu[512]; v3.u = bu[768];
  for (int t = 0; t < TCH - 4; t += 4) {
    bupk n0, n1, n2, n3;
    n0.u = bu[(t+4)*256]; n1.u = bu[(t+5)*256]; n2.u = bu[(t+6)*256]; n3.u = bu[(t+7)*256];
    APSTEP(v0, t); APSTEP(v1, t+1); APSTEP(v2, t+2); APSTEP(v3, t+3);
    v0 = n0; v1 = n1; v2 = n2; v3 = n3;
  }
  { const int t = TCH - 4; APSTEP(v0, t); APSTEP(v1, t+1); APSTEP(v2, t+2); APSTEP(v3, t+3); }
  #undef APSTEP
}

// ---------------------------------------------------------------- launch
extern "C" void kernel_launch(void* const* d_in, const int* in_sizes, int n_in,
                              void* d_out, int out_size, void* d_ws, size_t ws_size,
                              hipStream_t stream)
{
  const float* x      = (const float*)d_in[0];
  const float* nu_log = (const float*)d_in[1];
  const float* th_log = (const float*)d_in[2];
  const float* ga_log = (const float*)d_in[3];
  const float* B_re   = (const float*)d_in[4];
  const float* B_im   = (const float*)d_in[5];
  const float* C_re   = (const float*)d_in[6];
  const float* C_im   = (const float*)d_in[7];
  const float* Dmat   = (const float*)d_in[8];
  const float* W_fc   = (const float*)d_in[9];
  const float* b_fc   = (const float*)d_in[10];
  const float* W_proj = (const float*)d_in[11];
  const float* b_proj = (const float*)d_in[12];

  // ws layout (bytes):
  //   S_all : (M, 768) bf16 @ 0            201326592  [states interleaved | x_bf16]
  //   Bu    : (M, 512) bf16 @ 201326592    134217728  (dead after scan_apply)
  //   Hbuf  : (M,1024) bf16 @ 201326592    268435456  (overlaps Bu; written by gemm3 after Bu dead)
  //   Wb/Wz/Wfc/Wp/lam      @ 469762048    ~1.7 MB
  char* ws = (char*)d_ws;
  __bf16* S_all = (__bf16*)(ws);
  __bf16* Bu    = (__bf16*)(ws + 201326592);
  __bf16* Hbuf  = (__bf16*)(ws + 201326592);
  __bf16* Wb    = (__bf16*)(ws + 469762048);
  __bf16* Wz    = (__bf16*)(ws + 470024192);
  __bf16* Wfc   = (__bf16*)(ws + 470417408);
  __bf16* Wp    = (__bf16*)(ws + 470941696);
  float*  lam   = (float*) (ws + 471465984);
  if (ws_size < 471468032ULL) return;  // insufficient scratch: fail visibly

  // d_out (134 MB) doubles as scratch before the final GEMM overwrites all of it:
  char* ob = (char*)d_out;
  __bf16* Zbuf = (__bf16*)ob;                    // (M,256) bf16 = 67108864 B
  float2* carr = (float2*)(ob + 67108864);       // 16*64*256*8 = 2 MB
  float2* pre  = (float2*)(ob + 69206016);       // 2 MB  (end 71303168 < 134217728)

  prep_kernel<<<1024, 256, 0, stream>>>(nu_log, th_log, ga_log, B_re, B_im,
                                        C_re, C_im, Dmat, W_fc, W_proj,
                                        Wb, Wz, Wfc, Wp, lam);
  convert_x<<<M_SZ * DM / (256 * 4), 256, 0, stream>>>(x, S_all);

  // Bu = x @ [gamma*B_re ; gamma*B_im]^T   (M,512) bf16
  gemm_bt<256, 768, 512, 1, 4><<<(M_SZ / BM) * 4, 256, 0, stream>>>(S_all + 512, Wb, Bu, nullptr, nullptr);

  scan_carry <<<B_SZ * NCH, 256, 0, stream>>>(Bu, lam, carr);
  scan_prefix<<<B_SZ,       256, 0, stream>>>(carr, lam, pre);
  scan_apply <<<B_SZ * NCH, 256, 0, stream>>>(Bu, lam, pre, S_all);

  // z = Re(C s) + x D^T   -> bf16
  gemm_bt<768, 768, 256, 1, 2><<<(M_SZ / BM) * 2, 256, 0, stream>>>(S_all, Wz, Zbuf, nullptr, nullptr);
  // h = gelu(z W_fc + b_fc) -> bf16 (reuses Bu region)
  gemm_bt<256, 256, 1024, 2, 8><<<(M_SZ / BM) * 8, 256, 0, stream>>>(Zbuf, Wfc, Hbuf, b_fc, nullptr);
  // out = h W_proj + b_proj + x -> f32
  gemm_bt<1024, 1024, 256, 3, 2><<<(M_SZ / BM) * 2, 256, 0, stream>>>(Hbuf, Wp, d_out, b_proj, x);
}

// Round 5
// 744.104 us; speedup vs baseline: 1.3347x; 1.0534x over previous
//
#include <hip/hip_runtime.h>
#include <hip/hip_bf16.h>
#include <math.h>

// Problem dims
#define B_SZ 16
#define L_SZ 8192
#define DM   256
#define SS   256
#define FF   1024
#define M_SZ (B_SZ * L_SZ)      // 131072 rows
#define TCH  128                // scan chunk length
#define NCH  (L_SZ / TCH)       // 64 chunks per batch

// GEMM tile
#define BM 128
#define BN 128
#define BK 32

typedef __bf16 bf16x8 __attribute__((ext_vector_type(8)));
typedef float  f32x4  __attribute__((ext_vector_type(4)));

// ---------------------------------------------------------------- async 16B global->LDS
__device__ __forceinline__ void gld_lds16(const __bf16* g, __bf16* l) {
  __builtin_amdgcn_global_load_lds(
      (const __attribute__((address_space(1))) unsigned int*)g,
      (__attribute__((address_space(3))) unsigned int*)l, 16, 0, 0);
}

// ---------------------------------------------------------------- branchless exact-GELU
// erf via Abramowitz-Stegun 7.1.26 (max abs err 1.5e-7, well below bf16 output ulp).
__device__ __forceinline__ float gelu_exact_fast(float t) {
  const float at = fabsf(t);
  const float a  = at * 0.70710678118654752f;
  const float k  = __builtin_amdgcn_rcpf(fmaf(0.3275911f, a, 1.0f));
  float P = fmaf(1.061405429f, k, -1.453152027f);
  P = fmaf(P, k, 1.421413741f);
  P = fmaf(P, k, -0.284496736f);
  P = fmaf(P, k, 0.254829592f);
  P = P * k;
  const float e = __expf(-a * a);          // v_exp_f32 path
  const float half_t  = 0.5f * t;
  const float half_at = 0.5f * at;
  return fmaf(-half_at, P * e, half_t + half_at);
}

// ---------------------------------------------------------------- weight prep
__global__ void prep_kernel(const float* __restrict__ nu_log, const float* __restrict__ th_log,
                            const float* __restrict__ ga_log,
                            const float* __restrict__ B_re, const float* __restrict__ B_im,
                            const float* __restrict__ C_re, const float* __restrict__ C_im,
                            const float* __restrict__ Dmat,
                            const float* __restrict__ W_fc, const float* __restrict__ W_proj,
                            __bf16* __restrict__ Wb, __bf16* __restrict__ Wz,
                            __bf16* __restrict__ Wfc, __bf16* __restrict__ Wp,
                            float* __restrict__ lam)
{
  const int idx = blockIdx.x * 256 + threadIdx.x;   // 0 .. 262143
  if (idx < SS) {
    float la = expf(-expf(nu_log[idx]));
    float th = expf(th_log[idx]);
    lam[2*idx]   = la * cosf(th);
    lam[2*idx+1] = la * sinf(th);
  }
  if (idx < SS*DM) {
    int s = idx >> 8, d = idx & 255;
    float eg = expf(ga_log[s]);
    Wb[(size_t)(2*s)*DM + d]   = (__bf16)(B_re[idx] * eg);
    Wb[(size_t)(2*s+1)*DM + d] = (__bf16)(B_im[idx] * eg);
  }
  if (idx < DM*SS) {
    int o = idx >> 8, s = idx & 255;
    Wz[(size_t)o*768 + 2*s]     = (__bf16)( C_re[idx]);
    Wz[(size_t)o*768 + 2*s + 1] = (__bf16)(-C_im[idx]);
    Wz[(size_t)o*768 + 512 + s] = (__bf16)( Dmat[idx]);   // s acts as d here
  }
  if (idx < FF*DM) {
    int f = idx >> 8, d = idx & 255;                 // Wfc[f][d] = W_fc[d][f]
    Wfc[idx] = (__bf16)(W_fc[(size_t)d*FF + f]);
    int o = idx >> 10, f2 = idx & 1023;              // Wp[o][f2] = W_proj[f2][o]
    Wp[idx] = (__bf16)(W_proj[(size_t)f2*DM + o]);
  }
}

// ---------------------------------------------------------------- x (fp32) -> bf16 into S_all cols [512,768)
__global__ __launch_bounds__(256) void convert_x(const float* __restrict__ x, __bf16* __restrict__ S_all)
{
  const long i = ((long)blockIdx.x * 256 + threadIdx.x) * 4;  // over 33554432
  float4 v = *(const float4*)(x + i);
  const long m = i >> 8;
  const int  d = (int)(i & 255);
  union { __bf16 h[4]; uint2 u; } pk;
  pk.h[0] = (__bf16)v.x; pk.h[1] = (__bf16)v.y; pk.h[2] = (__bf16)v.z; pk.h[3] = (__bf16)v.w;
  *(uint2*)(S_all + m*768 + 512 + d) = pk.u;
}

// ---------------------------------------------------------------- bf16 MFMA GEMM, B^T (N,K) weights
// 2-phase double-buffered pipeline, 4 blocks/CU (TLP covers stalls: m114).
// Epilogue slimmed: 32-bit indices, hoisted bias, incremental row stride.
// MODE 1: store bf16 | MODE 2: bias + exact gelu -> bf16 | MODE 3: bias + resid -> f32
template<int K, int LDA, int LDC, int MODE, int NT>
__global__ __launch_bounds__(256, 4) void gemm_bt(const __bf16* __restrict__ A,
                                                  const __bf16* __restrict__ Bw,
                                                  void* __restrict__ Cout,
                                                  const float* __restrict__ bias,
                                                  const float* __restrict__ resid)
{
  __shared__ __attribute__((aligned(16))) __bf16 sA[2][BM * BK];
  __shared__ __attribute__((aligned(16))) __bf16 sB[2][BN * BK];

  const int tid  = threadIdx.x;
  const int lane = tid & 63;
  const int wave = tid >> 6;
  const int wm = (wave & 1) * 64;
  const int wn = (wave >> 1) * 64;

  constexpr int PER = 16 * NT;              // blocks per super-band (power of 2)
  const int blk = blockIdx.x;
  const int sb  = blk / PER;
  const int rem = blk & (PER - 1);
  const long m0 = (long)((sb << 4) + (rem & 15)) * BM;
  const long n0 = (long)(rem >> 4) * BN;

  f32x4 acc[4][4] = {};

  const int r  = tid >> 2;         // 0..63 (row within 64-row half)
  const int c8 = (tid & 3) * 8;    // k element offset of this thread's 16B chunk
  const __bf16* gA = A  + (m0 + r) * (long)LDA + c8;
  const __bf16* gB = Bw + (n0 + r) * (long)K   + c8;

  const int ar = lane & 15;
  const int ak = (lane >> 4) * 8;

  constexpr int NK = K / BK;

  // prologue: stage tile 0 into buf 0
  gld_lds16(gA,                  &sA[0][tid * 8]);
  gld_lds16(gA + 64 * (long)LDA, &sA[0][2048 + tid * 8]);
  gld_lds16(gB,                  &sB[0][tid * 8]);
  gld_lds16(gB + 64 * (long)K,   &sB[0][2048 + tid * 8]);
  gA += BK; gB += BK;
  __syncthreads();                 // vmcnt(0) drain + barrier

  int cur = 0;
  #pragma unroll 2
  for (int i = 0; i < NK; ++i) {
    if (i + 1 < NK) {              // issue next tile BEFORE compute
      const int nxt = cur ^ 1;
      gld_lds16(gA,                  &sA[nxt][tid * 8]);
      gld_lds16(gA + 64 * (long)LDA, &sA[nxt][2048 + tid * 8]);
      gld_lds16(gB,                  &sB[nxt][tid * 8]);
      gld_lds16(gB + 64 * (long)K,   &sB[nxt][2048 + tid * 8]);
      gA += BK; gB += BK;
    }

    bf16x8 af[4], bg[4];
    #pragma unroll
    for (int ii = 0; ii < 4; ++ii)
      af[ii] = *(const bf16x8*)&sA[cur][(wm + ii * 16 + ar) * BK + ak];
    #pragma unroll
    for (int j = 0; j < 4; ++j)
      bg[j] = *(const bf16x8*)&sB[cur][(wn + j * 16 + ar) * BK + ak];
    #pragma unroll
    for (int ii = 0; ii < 4; ++ii)
      #pragma unroll
      for (int j = 0; j < 4; ++j)
        acc[ii][j] = __builtin_amdgcn_mfma_f32_16x16x32_bf16(af[ii], bg[j], acc[ii][j], 0, 0, 0);

    __syncthreads();               // single barrier per K-step
    cur ^= 1;
  }

  // Epilogue: D row = (lane>>4)*4 + reg, col = lane&15   [measured m89/m91]
  // All output index spaces are < 2^31 elements -> 32-bit index math.
  const int col_l = lane & 15;
  const int row_l = (lane >> 4) * 4;
  const int n0i = (int)n0 + wn + col_l;
  const int m0i = (int)m0 + wm + row_l;

  float bcol[4];
  if constexpr (MODE != 1) {
    #pragma unroll
    for (int j = 0; j < 4; ++j) bcol[j] = bias[n0i + j * 16];
  }

  #pragma unroll
  for (int i = 0; i < 4; ++i) {
    const int row0 = m0i + i * 16;
    #pragma unroll
    for (int j = 0; j < 4; ++j) {
      int idx = row0 * LDC + n0i + j * 16;
      #pragma unroll
      for (int rr = 0; rr < 4; ++rr) {
        const float v = acc[i][j][rr];
        if constexpr (MODE == 1) {
          ((__bf16*)Cout)[idx] = (__bf16)v;
        } else if constexpr (MODE == 2) {
          ((__bf16*)Cout)[idx] = (__bf16)gelu_exact_fast(v + bcol[j]);
        } else {
          ((float*)Cout)[idx] = v + bcol[j] + resid[idx];
        }
        idx += LDC;
      }
    }
  }
}

// ---------------------------------------------------------------- scan kernels
// Bu layout: (M, 512) bf16, col 2s=re, 2s+1=im. Thread s loads 4B (2 bf16) per row.
#define CSTEP(vr, vi) { float nr_ = fmaf(lr, sr, fmaf(-li, si, (vr))); \
                        float ni_ = fmaf(lr, si, fmaf( li, sr, (vi))); sr = nr_; si = ni_; }

union bupk { unsigned int u; __bf16 h[2]; };

// Pass A: per-chunk carry with s_init = 0.
__global__ __launch_bounds__(256) void scan_carry(const __bf16* __restrict__ Bu,
                                                  const float* __restrict__ lam,
                                                  float2* __restrict__ carr)
{
  const int s  = threadIdx.x;
  const int bc = blockIdx.x;                       // b*NCH + c
  const float lr = lam[2*s], li = lam[2*s+1];
  const unsigned int* bu = (const unsigned int*)(Bu + (size_t)bc * (TCH * 512)) + s; // row stride 256 uints
  float sr = 0.f, si = 0.f;
  bupk v0, v1, v2, v3;
  v0.u = bu[0]; v1.u = bu[256]; v2.u = bu[512]; v3.u = bu[768];
  for (int t = 0; t < TCH - 4; t += 4) {
    bupk n0, n1, n2, n3;
    n0.u = bu[(t+4)*256]; n1.u = bu[(t+5)*256]; n2.u = bu[(t+6)*256]; n3.u = bu[(t+7)*256];
    CSTEP((float)v0.h[0], (float)v0.h[1]); CSTEP((float)v1.h[0], (float)v1.h[1]);
    CSTEP((float)v2.h[0], (float)v2.h[1]); CSTEP((float)v3.h[0], (float)v3.h[1]);
    v0 = n0; v1 = n1; v2 = n2; v3 = n3;
  }
  CSTEP((float)v0.h[0], (float)v0.h[1]); CSTEP((float)v1.h[0], (float)v1.h[1]);
  CSTEP((float)v2.h[0], (float)v2.h[1]); CSTEP((float)v3.h[0], (float)v3.h[1]);
  carr[(size_t)bc * 256 + s] = make_float2(sr, si);
}

// Pass B: exclusive prefix over chunks, operator p' = lam^TCH * p + carry
__global__ __launch_bounds__(256) void scan_prefix(const float2* __restrict__ carr,
                                                   const float* __restrict__ lam,
                                                   float2* __restrict__ pre)
{
  const int s = threadIdx.x;
  const int b = blockIdx.x;
  float ar = lam[2*s], ai = lam[2*s+1];            // lam^TCH by squaring: TCH=128=2^7
  #pragma unroll
  for (int i = 0; i < 7; ++i) { float nr = ar*ar - ai*ai, ni = 2.f*ar*ai; ar = nr; ai = ni; }
  float pr = 0.f, pi = 0.f;
  for (int c = 0; c < NCH; ++c) {
    const size_t off = (size_t)(b * NCH + c) * 256 + s;
    pre[off] = make_float2(pr, pi);
    float2 cv = carr[off];
    float nr = fmaf(ar, pr, fmaf(-ai, pi, cv.x));
    float ni = fmaf(ar, pi, fmaf( ai, pr, cv.y));
    pr = nr; pi = ni;
  }
}

// Pass C: re-scan with init = prefix, write inclusive states as bf16 into S_all cols [0,512)
__global__ __launch_bounds__(256) void scan_apply(const __bf16* __restrict__ Bu,
                                                  const float* __restrict__ lam,
                                                  const float2* __restrict__ pre,
                                                  __bf16* __restrict__ S_all)
{
  const int s  = threadIdx.x;
  const int bc = blockIdx.x;
  const float lr = lam[2*s], li = lam[2*s+1];
  float2 p = pre[(size_t)bc * 256 + s];
  float sr = p.x, si = p.y;
  const unsigned int* bu = (const unsigned int*)(Bu + (size_t)bc * (TCH * 512)) + s;
  __bf16* outp = S_all + (size_t)bc * (TCH * 768) + 2 * s;
  #define APSTEP(v, t) { CSTEP((float)(v).h[0], (float)(v).h[1]); \
    union { __bf16 h[2]; unsigned int u; } pk_; pk_.h[0] = (__bf16)sr; pk_.h[1] = (__bf16)si; \
    *(unsigned int*)(outp + (size_t)(t) * 768) = pk_.u; }
  bupk v0, v1, v2, v3;
  v0.u = bu[0]; v1.u = bu[256]; v2.u = bu[512]; v3.u = bu[768];
  for (int t = 0; t < TCH - 4; t += 4) {
    bupk n0, n1, n2, n3;
    n0.u = bu[(t+4)*256]; n1.u = bu[(t+5)*256]; n2.u = bu[(t+6)*256]; n3.u = bu[(t+7)*256];
    APSTEP(v0, t); APSTEP(v1, t+1); APSTEP(v2, t+2); APSTEP(v3, t+3);
    v0 = n0; v1 = n1; v2 = n2; v3 = n3;
  }
  { const int t = TCH - 4; APSTEP(v0, t); APSTEP(v1, t+1); APSTEP(v2, t+2); APSTEP(v3, t+3); }
  #undef APSTEP
}

// ---------------------------------------------------------------- launch
extern "C" void kernel_launch(void* const* d_in, const int* in_sizes, int n_in,
                              void* d_out, int out_size, void* d_ws, size_t ws_size,
                              hipStream_t stream)
{
  const float* x      = (const float*)d_in[0];
  const float* nu_log = (const float*)d_in[1];
  const float* th_log = (const float*)d_in[2];
  const float* ga_log = (const float*)d_in[3];
  const float* B_re   = (const float*)d_in[4];
  const float* B_im   = (const float*)d_in[5];
  const float* C_re   = (const float*)d_in[6];
  const float* C_im   = (const float*)d_in[7];
  const float* Dmat   = (const float*)d_in[8];
  const float* W_fc   = (const float*)d_in[9];
  const float* b_fc   = (const float*)d_in[10];
  const float* W_proj = (const float*)d_in[11];
  const float* b_proj = (const float*)d_in[12];

  // ws layout (bytes):
  //   S_all : (M, 768) bf16 @ 0            201326592  [states interleaved | x_bf16]
  //   Bu    : (M, 512) bf16 @ 201326592    134217728  (dead after scan_apply)
  //   Hbuf  : (M,1024) bf16 @ 201326592    268435456  (overlaps Bu; written by gemm3 after Bu dead)
  //   Wb/Wz/Wfc/Wp/lam      @ 469762048    ~1.7 MB
  char* ws = (char*)d_ws;
  __bf16* S_all = (__bf16*)(ws);
  __bf16* Bu    = (__bf16*)(ws + 201326592);
  __bf16* Hbuf  = (__bf16*)(ws + 201326592);
  __bf16* Wb    = (__bf16*)(ws + 469762048);
  __bf16* Wz    = (__bf16*)(ws + 470024192);
  __bf16* Wfc   = (__bf16*)(ws + 470417408);
  __bf16* Wp    = (__bf16*)(ws + 470941696);
  float*  lam   = (float*) (ws + 471465984);
  if (ws_size < 471468032ULL) return;  // insufficient scratch: fail visibly

  // d_out (134 MB) doubles as scratch before the final GEMM overwrites all of it:
  char* ob = (char*)d_out;
  __bf16* Zbuf = (__bf16*)ob;                    // (M,256) bf16 = 67108864 B
  float2* carr = (float2*)(ob + 67108864);       // 16*64*256*8 = 2 MB
  float2* pre  = (float2*)(ob + 69206016);       // 2 MB  (end 71303168 < 134217728)

  prep_kernel<<<1024, 256, 0, stream>>>(nu_log, th_log, ga_log, B_re, B_im,
                                        C_re, C_im, Dmat, W_fc, W_proj,
                                        Wb, Wz, Wfc, Wp, lam);
  convert_x<<<M_SZ * DM / (256 * 4), 256, 0, stream>>>(x, S_all);

  // Bu = x @ [gamma*B_re ; gamma*B_im]^T   (M,512) bf16
  gemm_bt<256, 768, 512, 1, 4><<<(M_SZ / BM) * 4, 256, 0, stream>>>(S_all + 512, Wb, Bu, nullptr, nullptr);

  scan_carry <<<B_SZ * NCH, 256, 0, stream>>>(Bu, lam, carr);
  scan_prefix<<<B_SZ,       256, 0, stream>>>(carr, lam, pre);
  scan_apply <<<B_SZ * NCH, 256, 0, stream>>>(Bu, lam, pre, S_all);

  // z = Re(C s) + x D^T   -> bf16
  gemm_bt<768, 768, 256, 1, 2><<<(M_SZ / BM) * 2, 256, 0, stream>>>(S_all, Wz, Zbuf, nullptr, nullptr);
  // h = gelu(z W_fc + b_fc) -> bf16 (reuses Bu region)
  gemm_bt<256, 256, 1024, 2, 8><<<(M_SZ / BM) * 8, 256, 0, stream>>>(Zbuf, Wfc, Hbuf, b_fc, nullptr);
  // out = h W_proj + b_proj + x -> f32
  gemm_bt<1024, 1024, 256, 3, 2><<<(M_SZ / BM) * 2, 256, 0, stream>>>(Hbuf, Wp, d_out, b_proj, x);
}